// Round 15
// baseline (248.942 us; speedup 1.0000x reference)
//
#include <hip/hip_runtime.h>
#include <hip/hip_bf16.h>
#include <stdint.h>

typedef __bf16 bf16;
typedef __attribute__((ext_vector_type(8))) __bf16 bf16x8;
typedef __attribute__((ext_vector_type(4))) __bf16 bf16x4;
typedef __attribute__((ext_vector_type(4))) float  f32x4;

// ---- async global->LDS, 16B per lane, dest = wave-uniform base (+ lane*16 in HW) ----
static __device__ __forceinline__ void gll16(const void* g, void* lds_base) {
  __builtin_amdgcn_global_load_lds((__attribute__((address_space(1))) void*)g,
                                   (__attribute__((address_space(3))) void*)lds_base,
                                   16, 0, 0);
}

#define BARR  __builtin_amdgcn_s_barrier()
#define VMW(N) asm volatile("s_waitcnt vmcnt(" #N ")" ::: "memory")
#define LGKM0 do { asm volatile("s_waitcnt lgkmcnt(0)" ::: "memory");          \
                   __builtin_amdgcn_sched_barrier(0); } while (0)

// ============================================================================
// proj8: 8-phase 256x256 BT-GEMM (R12-measured ~860 TF). Unchanged.
// ============================================================================
__global__ __launch_bounds__(512, 2) void proj8(const bf16* __restrict__ a0,
                                                const bf16* __restrict__ a1,
                                                const bf16* __restrict__ b0,
                                                const bf16* __restrict__ b1,
                                                bf16* __restrict__ c0,
                                                bf16* __restrict__ c1) {
  extern __shared__ char smem[];
  char* ldsA = smem;
  char* ldsB = smem + 65536;

  const int tid = threadIdx.x;
  const int lane = tid & 63, wave = tid >> 6;
  const int lo = lane & 15, hi = lane >> 4;
  const int wmi = wave >> 2, wni = wave & 3;
  const int swz = (lo & 7) << 4;

  const int nwg = gridDim.x;
  const int id = (blockIdx.x % 8) * (nwg >> 3) + blockIdx.x / 8;
  const int seg = id >> 8, idl = id & 255;
  const int row0 = (idl >> 2) * 256, col0 = (idl & 3) * 256;
  const bf16* Ap = (seg ? a1 : a0) + (size_t)row0 * 1024;
  const bf16* Bp = (seg ? b1 : b0) + (size_t)col0 * 1024;
  bf16* Cb = seg ? c1 : c0;

  const char* aSrc[2];
  const char* bSrc[2];
  int ldsOff[2];
#pragma unroll
  for (int rr = 0; rr < 2; ++rr) {
    const int x = rr * 8192 + tid * 16;
    const int lr = x >> 7;
    const int colx = (x & 127) ^ ((lr & 7) << 4);
    aSrc[rr] = (const char*)Ap + (size_t)(((lr >> 6) << 7) | (lr & 63)) * 2048 + colx;
    bSrc[rr] = (const char*)Bp + (size_t)(((lr >> 5) << 6) | (lr & 31)) * 2048 + colx;
    ldsOff[rr] = rr * 8192 + wave * 1024;
  }
  auto stA = [&](int h, int buf, int t) {
    const int tc = t > 15 ? 15 : t;
#pragma unroll
    for (int rr = 0; rr < 2; ++rr)
      gll16(aSrc[rr] + h * 131072 + tc * 128,
            ldsA + buf * 32768 + h * 16384 + ldsOff[rr]);
  };
  auto stB = [&](int h, int buf, int t) {
    const int tc = t > 15 ? 15 : t;
#pragma unroll
    for (int rr = 0; rr < 2; ++rr)
      gll16(bSrc[rr] + h * 65536 + tc * 128,
            ldsB + buf * 32768 + h * 16384 + ldsOff[rr]);
  };

  f32x4 acc[8][4] = {};
  bf16x8 af[4][2], bq0[2][2], bq1[2][2];

  auto rdA = [&](int mq, int buf) {
#pragma unroll
    for (int i = 0; i < 4; ++i) {
      const int lr = wmi * 64 + i * 16 + lo;
#pragma unroll
      for (int kh = 0; kh < 2; ++kh)
        af[i][kh] = *(const bf16x8*)(ldsA + buf * 32768 + mq * 16384 +
                                     lr * 128 + ((kh * 64 + hi * 16) ^ swz));
    }
  };
  auto rdB = [&](bf16x8 bq[2][2], int nq, int buf) {
#pragma unroll
    for (int n = 0; n < 2; ++n) {
      const int lr = wni * 32 + n * 16 + lo;
#pragma unroll
      for (int kh = 0; kh < 2; ++kh)
        bq[n][kh] = *(const bf16x8*)(ldsB + buf * 32768 + nq * 16384 +
                                     lr * 128 + ((kh * 64 + hi * 16) ^ swz));
    }
  };
  auto mma = [&](bf16x8 bq[2][2], int mq, int nq) {
    __builtin_amdgcn_s_setprio(1);
#pragma unroll
    for (int i = 0; i < 4; ++i)
#pragma unroll
      for (int n = 0; n < 2; ++n)
#pragma unroll
        for (int kh = 0; kh < 2; ++kh)
          acc[mq * 4 + i][nq * 2 + n] = __builtin_amdgcn_mfma_f32_16x16x32_bf16(
              af[i][kh], bq[n][kh], acc[mq * 4 + i][nq * 2 + n], 0, 0, 0);
    __builtin_amdgcn_s_setprio(0);
  };

  stA(0, 0, 0); stB(1, 0, 0); stA(1, 0, 0); stB(0, 0, 0);
  stA(0, 1, 1); stB(1, 1, 1); stA(1, 1, 1);
  VMW(6); BARR;

  for (int j = 0; j < 8; ++j) {
    const int t1 = 2 * j + 1, t2 = 2 * j + 2, t3 = 2 * j + 3;
    rdA(0, 0); rdB(bq0, 0, 0); stB(0, 1, t1);
    BARR; LGKM0; mma(bq0, 0, 0); BARR;
    rdB(bq1, 1, 0); stA(0, 0, t2);
    BARR; LGKM0; mma(bq1, 0, 1); BARR;
    rdA(1, 0); stB(1, 0, t2);
    BARR; LGKM0; mma(bq1, 1, 1); BARR;
    stA(1, 0, t2);
    BARR; LGKM0; mma(bq0, 1, 0); VMW(6); BARR;
    rdA(0, 1); rdB(bq0, 0, 1); stB(0, 0, t2);
    BARR; LGKM0; mma(bq0, 0, 0); BARR;
    rdB(bq1, 1, 1); stA(0, 1, t3);
    BARR; LGKM0; mma(bq1, 0, 1); BARR;
    rdA(1, 1); stB(1, 1, t3);
    BARR; LGKM0; mma(bq1, 1, 1); BARR;
    stA(1, 1, t3);
    BARR; LGKM0; mma(bq0, 1, 0); VMW(6); BARR;
  }

  if (!seg) {
#pragma unroll
    for (int m = 0; m < 8; ++m)
#pragma unroll
      for (int n = 0; n < 4; ++n) {
        const int c = col0 + wni * 64 + n * 16 + lo;
        const int rbase = row0 + wmi * 128 + m * 16 + hi * 4;
#pragma unroll
        for (int j = 0; j < 4; ++j)
          Cb[(size_t)(rbase + j) * 1024 + c] = (bf16)acc[m][n][j];
      }
  } else {
#pragma unroll
    for (int m = 0; m < 8; ++m)
#pragma unroll
      for (int n = 0; n < 4; ++n) {
        const int r = row0 + wmi * 128 + m * 16 + hi * 4;
        const int c = col0 + wni * 64 + n * 16 + lo;
        const int bb = r >> 10, tt = r & 1023;
        bf16x4 h = { (bf16)acc[m][n][0], (bf16)acc[m][n][1],
                     (bf16)acc[m][n][2], (bf16)acc[m][n][3] };
        *(bf16x4*)(Cb + ((size_t)bb << 20) + ((size_t)c << 10) + tt) = h;
      }
  }
  asm volatile("s_waitcnt vmcnt(0)" ::: "memory");
}

// ============================================================================
// 2-phase 128x128 BT-GEMM (BK=32), R14-proven core (qk / pv only now).
// VARIANT 2: qk S=BT(Y,Xk)/batch; causal writes 0, pad -inf; zero-fill iff
//   jt>=it+2. VARIANT 3: pv out f32, nt=min(32,4*it+5).
// ============================================================================
template <int VARIANT>
__global__ __launch_bounds__(512, 2) void gemm8(const bf16* __restrict__ a0,
                                                const bf16* __restrict__ b0,
                                                bf16* __restrict__ c0,
                                                float* __restrict__ Cf,
                                                const int* __restrict__ pad) {
  constexpr int TM = 128, TN = 128;
  constexpr int ABYTES = TM * 64;
  constexpr int BBYTES = TN * 64;
  constexpr int FI = TM / 64;                 // A frags per phase
  constexpr int FN = TN / 64;                 // B frags per wave
  extern __shared__ char smem[];
  char* ldsA = smem;
  char* ldsB = smem + 2 * ABYTES;

  const int tid = threadIdx.x;
  const int lane = tid & 63, wave = tid >> 6;
  const int lo = lane & 15, hi = lane >> 4;
  const int wmi = wave >> 2, wni = wave & 3;
  const int swz = ((lo >> 1) & 3) << 4;

  const int nwg = gridDim.x;
  const int id = (blockIdx.x % 8) * (nwg >> 3) + blockIdx.x / 8;

  const int batch = id >> 6;
  const int it = (id >> 3) & 7, jt = id & 7;
  const int row0 = it * 128, col0 = jt * 128;
  const int nt = (VARIANT == 3) ? min(32, 4 * it + 5) : 32;
  if (VARIANT == 2 && jt >= it + 2) {          // fully above causal boundary
    bf16* Sb = c0 + ((size_t)batch << 20);
    bf16x8 z = {};
#pragma unroll
    for (int q = 0; q < (TM * TN) / (512 * 8); ++q) {
      const int off = (q * 512 + tid) * 8;
      *(bf16x8*)(Sb + (size_t)(row0 + (off >> 7)) * 1024 + col0 + (off & 127)) = z;
    }
    return;
  }
  const bf16* Ap = a0 + ((size_t)batch << 20) + (size_t)row0 * 1024;
  const bf16* Bp = b0 + ((size_t)batch << 20) + (size_t)col0 * 1024;
  bf16* Cb = c0;
  const int ntm1 = nt - 1;

  auto stgA = [&](int tidx, int slot) {
    const int tc = tidx > ntm1 ? ntm1 : tidx;
    const int x  = tid * 16;
    const int xs = x ^ (((x >> 7) & 3) << 4);
    gll16((const char*)Ap + (size_t)(xs >> 6) * 2048 + (size_t)tc * 64 + (xs & 63),
          ldsA + slot * ABYTES + wave * 1024);
  };
  auto stgB = [&](int tidx, int slot) {
    const int tc = tidx > ntm1 ? ntm1 : tidx;
    const int x  = tid * 16;
    const int xs = x ^ (((x >> 7) & 3) << 4);
    gll16((const char*)Bp + (size_t)(xs >> 6) * 2048 + (size_t)tc * 64 + (xs & 63),
          ldsB + slot * BBYTES + wave * 1024);
  };

  f32x4 acc[2 * FI][FN] = {};
  bf16x8 af[FI], bfr[FN];

  auto rdA = [&](int mh, int slot) {
#pragma unroll
    for (int i = 0; i < FI; ++i) {
      const int row = wmi * (TM / 2) + mh * (TM / 4) + i * 16 + lo;
      af[i] = *(const bf16x8*)(ldsA + slot * ABYTES + ((row * 64 + hi * 16) ^ swz));
    }
  };
  auto rdB = [&](int slot) {
#pragma unroll
    for (int n = 0; n < FN; ++n) {
      const int row = wni * (TN / 4) + n * 16 + lo;
      bfr[n] = *(const bf16x8*)(ldsB + slot * BBYTES + ((row * 64 + hi * 16) ^ swz));
    }
  };
  auto mmaQ = [&](int mh) {
    __builtin_amdgcn_s_setprio(1);
#pragma unroll
    for (int i = 0; i < FI; ++i)
#pragma unroll
      for (int n = 0; n < FN; ++n)
        acc[mh * FI + i][n] = __builtin_amdgcn_mfma_f32_16x16x32_bf16(
            af[i], bfr[n], acc[mh * FI + i][n], 0, 0, 0);
    __builtin_amdgcn_s_setprio(0);
  };

  stgB(0, 0);
  stgA(0, 0);
  stgB(1, 1);
  VMW(1);
  BARR;

#pragma unroll 2
  for (int u = 0; u < nt; ++u) {
    const int cur = u & 1;
    rdA(0, cur);
    rdB(cur);
    stgA(u + 1, cur ^ 1);
    BARR; LGKM0;
    mmaQ(0);
    BARR;
    rdA(1, cur);
    stgB(u + 2, cur);
    BARR; LGKM0;
    mmaQ(1);
    VMW(1);
    BARR;
  }

  if (VARIANT == 2) {
    const float NINF = -__builtin_inff();
#pragma unroll
    for (int n = 0; n < FN; ++n) {
      const int s = col0 + wni * (TN / 4) + n * 16 + lo;
      const int pd = pad[(batch << 10) + s];
#pragma unroll
      for (int m = 0; m < 2 * FI; ++m) {
        const int tbase = row0 + wmi * (TM / 2) + m * 16 + hi * 4;
#pragma unroll
        for (int j = 0; j < 4; ++j) {
          float v = acc[m][n][j] * 0.03125f;
          if (s > tbase + j + 1) v = 0.f;
          else if (pd != 0) v = NINF;
          Cb[((size_t)batch << 20) + (size_t)(tbase + j) * 1024 + s] = (bf16)v;
        }
      }
    }
  } else {
#pragma unroll
    for (int m = 0; m < 2 * FI; ++m)
#pragma unroll
      for (int n = 0; n < FN; ++n) {
        const int h2 = col0 + wni * (TN / 4) + n * 16 + lo;
        const int tbase = row0 + wmi * (TM / 2) + m * 16 + hi * 4;
#pragma unroll
        for (int j = 0; j < 4; ++j)
          Cf[((size_t)batch << 20) + (size_t)(tbase + j) * 1024 + h2] = acc[m][n][j];
      }
  }
  asm volatile("s_waitcnt vmcnt(0)" ::: "memory");
}

// ============================================================================
// MERGED cvt3 + P-GEMM dispatch. The standalone 16-block P-GEMM left ~94% of
// the GPU idle for its ~30 us critical path; it only depends on cvtWT, not on
// cvt3, so it hides entirely under cvt3's ~46 us HBM-bound stream.
// Blocks [0,12288): fp32->bf16 (512 thr x 8 elems; seg = id/4096).
// Blocks [12288,12304): P = BT(WkT, WqT), the R11-proven 2-phase 256x256
// BK=32 GEMM (64 KiB LDS), idl = id-12288.
// Grid 12304 = 8*1538 (XCD swizzle bijective).
// ============================================================================
__global__ __launch_bounds__(512, 2) void cvtP_kernel(const float* __restrict__ s0,
                                                      const float* __restrict__ s1,
                                                      const float* __restrict__ s2,
                                                      bf16* __restrict__ d0,
                                                      bf16* __restrict__ d1,
                                                      bf16* __restrict__ d2,
                                                      const bf16* __restrict__ WkT,
                                                      const bf16* __restrict__ WqT,
                                                      bf16* __restrict__ P) {
  extern __shared__ char smem[];
  const int nwg = gridDim.x;
  const int id = (blockIdx.x % 8) * (nwg >> 3) + blockIdx.x / 8;
  const int tid = threadIdx.x;

  if (id < 12288) {
    const int seg = id / 4096, blk = id % 4096;
    const float* src = seg == 0 ? s0 : (seg == 1 ? s1 : s2);
    bf16* dst = seg == 0 ? d0 : (seg == 1 ? d1 : d2);
    const int i = (blk * 512 + tid) * 8;
    const f32x4 a = *(const f32x4*)(src + i);
    const f32x4 b = *(const f32x4*)(src + i + 4);
    bf16x8 o = { (bf16)a[0], (bf16)a[1], (bf16)a[2], (bf16)a[3],
                 (bf16)b[0], (bf16)b[1], (bf16)b[2], (bf16)b[3] };
    *(bf16x8*)(dst + i) = o;
    return;
  }

  // ---- P-GEMM path (R11-proven 2-phase 256x256, BK=32) ----
  constexpr int ABYTES = 16384;            // 256 rows x 32 K x 2B
  char* ldsA = smem;
  char* ldsB = smem + 2 * ABYTES;
  const int lane = tid & 63, wave = tid >> 6;
  const int lo = lane & 15, hi = lane >> 4;
  const int wmi = wave >> 2, wni = wave & 3;
  const int swz = ((lo >> 1) & 3) << 4;

  const int idl = id - 12288;              // [0,16)
  const int row0 = (idl >> 2) * 256, col0 = (idl & 3) * 256;
  const bf16* Ap = WkT + (size_t)row0 * 1024;
  const bf16* Bp = WqT + (size_t)col0 * 1024;

  auto stg = [&](const bf16* base, char* ldsOp, int tidx, int slot) {
    const int tc = tidx > 31 ? 31 : tidx;
#pragma unroll
    for (int r = 0; r < 2; ++r) {
      const int x  = (r * 512 + tid) * 16;
      const int xs = x ^ (((x >> 7) & 3) << 4);
      gll16((const char*)base + (size_t)(xs >> 6) * 2048 + (size_t)tc * 64 + (xs & 63),
            ldsOp + slot * ABYTES + r * 8192 + wave * 1024);
    }
  };

  f32x4 acc[8][4] = {};
  bf16x8 af[4], bfr[4];

  auto rdA = [&](int mh, int slot) {
#pragma unroll
    for (int i = 0; i < 4; ++i) {
      const int row = wmi * 128 + mh * 64 + i * 16 + lo;
      af[i] = *(const bf16x8*)(ldsA + slot * ABYTES + ((row * 64 + hi * 16) ^ swz));
    }
  };
  auto rdB = [&](int slot) {
#pragma unroll
    for (int n = 0; n < 4; ++n) {
      const int row = wni * 64 + n * 16 + lo;
      bfr[n] = *(const bf16x8*)(ldsB + slot * ABYTES + ((row * 64 + hi * 16) ^ swz));
    }
  };
  auto mmaQ = [&](int mh) {
    __builtin_amdgcn_s_setprio(1);
#pragma unroll
    for (int i = 0; i < 4; ++i)
#pragma unroll
      for (int n = 0; n < 4; ++n)
        acc[mh * 4 + i][n] = __builtin_amdgcn_mfma_f32_16x16x32_bf16(
            af[i], bfr[n], acc[mh * 4 + i][n], 0, 0, 0);
    __builtin_amdgcn_s_setprio(0);
  };

  stg(Bp, ldsB, 0, 0);
  stg(Ap, ldsA, 0, 0);
  stg(Bp, ldsB, 1, 1);
  VMW(2);
  BARR;

#pragma unroll 2
  for (int u = 0; u < 32; ++u) {
    const int cur = u & 1;
    rdA(0, cur);
    rdB(cur);
    stg(Ap, ldsA, u + 1, cur ^ 1);
    BARR; LGKM0;
    mmaQ(0);
    BARR;
    rdA(1, cur);
    stg(Bp, ldsB, u + 2, cur);
    BARR; LGKM0;
    mmaQ(1);
    VMW(2);
    BARR;
  }

#pragma unroll
  for (int m = 0; m < 8; ++m)
#pragma unroll
    for (int n = 0; n < 4; ++n) {
      const int c = col0 + wni * 64 + n * 16 + lo;
      const int rbase = row0 + wmi * 128 + m * 16 + hi * 4;
#pragma unroll
      for (int j = 0; j < 4; ++j)
        P[(size_t)(rbase + j) * 1024 + c] = (bf16)acc[m][n][j];
    }
  asm volatile("s_waitcnt vmcnt(0)" ::: "memory");
}

// ---- weights: Wq,Wk -> TRANSPOSED bf16 (for the P-GEMM); Wv -> straight ----
__global__ __launch_bounds__(256) void cvtWT_kernel(const float* __restrict__ Wq,
                                                    const float* __restrict__ Wk,
                                                    const float* __restrict__ Wv,
                                                    bf16* __restrict__ WqT,
                                                    bf16* __restrict__ WkT,
                                                    bf16* __restrict__ Wvb) {
  const int t = threadIdx.x;
  if (blockIdx.x >= 512) {
    const int i = ((blockIdx.x - 512) * 256 + t) * 8;
    const f32x4 a = *(const f32x4*)(Wv + i);
    const f32x4 b = *(const f32x4*)(Wv + i + 4);
    bf16x8 o = { (bf16)a[0], (bf16)a[1], (bf16)a[2], (bf16)a[3],
                 (bf16)b[0], (bf16)b[1], (bf16)b[2], (bf16)b[3] };
    *(bf16x8*)(Wvb + i) = o;
    return;
  }
  const int m = blockIdx.x >> 8;
  const float* src = m ? Wk : Wq;
  bf16* dst = m ? WkT : WqT;
  const int tile = blockIdx.x & 255;
  const int tr = (tile >> 4) * 64, tc = (tile & 15) * 64;
  __shared__ bf16 s[64][72];
#pragma unroll
  for (int it = 0; it < 4; ++it) {
    const int row = it * 16 + (t >> 4), col = (t & 15) * 4;
    const f32x4 v = *(const f32x4*)(src + (size_t)(tr + row) * 1024 + tc + col);
#pragma unroll
    for (int j = 0; j < 4; ++j) s[col + j][row] = (bf16)v[j];
  }
  __syncthreads();
  const int c = t >> 2, rb = (t & 3) * 16;
  bf16* d = dst + (size_t)(tc + c) * 1024 + tr + rb;
  *(bf16x8*)(d)     = *(const bf16x8*)&s[c][rb];
  *(bf16x8*)(d + 8) = *(const bf16x8*)&s[c][rb + 8];
}

// ---- row softmax in place over valid prefix w = t+2 (causal tail stays 0) ----
__global__ __launch_bounds__(256) void softmax_kernel(bf16* __restrict__ S) {
  const int row  = blockIdx.x * 4 + (threadIdx.x >> 6);
  const int lane = threadIdx.x & 63;
  const int t = row & 1023;
  const int w = min(1024, t + 2);
  const bool act = lane * 16 < w;
  bf16* r = S + (size_t)row * 1024 + lane * 16;
  bf16x8 v0 = {}, v1 = {};
  float f[16];
#pragma unroll
  for (int j = 0; j < 16; ++j) f[j] = -1e30f;
  if (act) {
    v0 = *(const bf16x8*)r;
    v1 = *(const bf16x8*)(r + 8);
#pragma unroll
    for (int j = 0; j < 16; ++j)
      if (lane * 16 + j < w) f[j] = (float)(j < 8 ? v0[j] : v1[j - 8]);
  }
  float m = f[0];
#pragma unroll
  for (int j = 1; j < 16; ++j) m = fmaxf(m, f[j]);
#pragma unroll
  for (int o = 32; o; o >>= 1) m = fmaxf(m, __shfl_xor(m, o, 64));
  float sum = 0.f;
  float e[16];
#pragma unroll
  for (int j = 0; j < 16; ++j) { e[j] = __expf(f[j] - m); sum += e[j]; }
#pragma unroll
  for (int o = 32; o; o >>= 1) sum += __shfl_xor(sum, o, 64);
  const float inv = 1.0f / sum;
  if (act) {
#pragma unroll
    for (int j = 0; j < 8; ++j) {
      v0[j] = (bf16)(lane * 16 + j < w ? e[j] * inv : 0.f);
      v1[j] = (bf16)(lane * 16 + 8 + j < w ? e[8 + j] * inv : 0.f);
    }
    *(bf16x8*)r = v0;
    *(bf16x8*)(r + 8) = v1;
  }
}

extern "C" void kernel_launch(void* const* d_in, const int* in_sizes, int n_in,
                              void* d_out, int out_size, void* d_ws, size_t ws_size,
                              hipStream_t stream) {
  const float* key   = (const float*)d_in[0];
  const float* query = (const float*)d_in[1];
  const float* value = (const float*)d_in[2];
  const int*   pad   = (const int*)d_in[3];
  const float* Wk    = (const float*)d_in[4];
  const float* Wq    = (const float*)d_in[5];
  const float* Wv    = (const float*)d_in[6];
  float* out = (float*)d_out;

  // ws (bf16 elems): WqT,WkT,Wvb,P (1M each) | Y 16M | vT 16M | S 16M
  // Scratch: Xq = S slot (not live until qk writes S); Xk,Xv = d_out.
  bf16* WqT = (bf16*)d_ws;
  bf16* WkT = WqT + (1 << 20);
  bf16* Wvb = WkT + (1 << 20);
  bf16* P   = Wvb + (1 << 20);
  bf16* Y   = P   + (1 << 20);
  bf16* vT  = Y   + (16 << 20);
  bf16* S   = vT  + (16 << 20);
  bf16* Xq  = S;
  bf16* Xk  = (bf16*)d_out;
  bf16* Xv  = Xk + (16 << 20);

  hipFuncSetAttribute(reinterpret_cast<const void*>(&proj8),
                      hipFuncAttributeMaxDynamicSharedMemorySize, 131072);
  hipFuncSetAttribute(reinterpret_cast<const void*>(&cvtP_kernel),
                      hipFuncAttributeMaxDynamicSharedMemorySize, 65536);
  hipFuncSetAttribute(reinterpret_cast<const void*>(&gemm8<2>),
                      hipFuncAttributeMaxDynamicSharedMemorySize, 32768);
  hipFuncSetAttribute(reinterpret_cast<const void*>(&gemm8<3>),
                      hipFuncAttributeMaxDynamicSharedMemorySize, 32768);

  cvtWT_kernel<<<1024, 256, 0, stream>>>(Wq, Wk, Wv, WqT, WkT, Wvb);
  // merged: inputs fp32->bf16 (12288 blocks) || P = BT(WkT,WqT) (16 blocks)
  cvtP_kernel<<<12304, 512, 65536, stream>>>(query, key, value, Xq, Xk, Xv,
                                             WkT, WqT, P);

  // merged 8-phase projections: seg0 Y = BT(Xq, P); seg1 vT = BT(Xv, Wvb)^T
  proj8<<<512, 512, 131072, stream>>>(Xq, Xv, P, Wvb, Y, vT);

  // S = BT(Y, Xk) per batch (== q k^T), 128x128 tiles
  gemm8<2><<<1024, 512, 32768, stream>>>(Y, Xk, S, nullptr, pad);
  softmax_kernel<<<4096, 256, 0, stream>>>(S);
  gemm8<3><<<1024, 512, 32768, stream>>>(S, vT, nullptr, out, nullptr);
}

// Round 16
// 222.742 us; speedup vs baseline: 1.1176x; 1.1176x over previous
//
#include <hip/hip_runtime.h>
#include <hip/hip_bf16.h>
#include <stdint.h>

typedef __bf16 bf16;
typedef __attribute__((ext_vector_type(8))) __bf16 bf16x8;
typedef __attribute__((ext_vector_type(4))) __bf16 bf16x4;
typedef __attribute__((ext_vector_type(4))) float  f32x4;

// ---- async global->LDS, 16B per lane, dest = wave-uniform base (+ lane*16 in HW) ----
static __device__ __forceinline__ void gll16(const void* g, void* lds_base) {
  __builtin_amdgcn_global_load_lds((__attribute__((address_space(1))) void*)g,
                                   (__attribute__((address_space(3))) void*)lds_base,
                                   16, 0, 0);
}

#define BARR  __builtin_amdgcn_s_barrier()
#define VMW(N) asm volatile("s_waitcnt vmcnt(" #N ")" ::: "memory")
#define LGKM0 do { asm volatile("s_waitcnt lgkmcnt(0)" ::: "memory");          \
                   __builtin_amdgcn_sched_barrier(0); } while (0)

// ============================================================================
// proj8: 8-phase 256x256 BT-GEMM (R12/R14-measured ~860 TF). Unchanged.
// ============================================================================
__global__ __launch_bounds__(512, 2) void proj8(const bf16* __restrict__ a0,
                                                const bf16* __restrict__ a1,
                                                const bf16* __restrict__ b0,
                                                const bf16* __restrict__ b1,
                                                bf16* __restrict__ c0,
                                                bf16* __restrict__ c1) {
  extern __shared__ char smem[];
  char* ldsA = smem;
  char* ldsB = smem + 65536;

  const int tid = threadIdx.x;
  const int lane = tid & 63, wave = tid >> 6;
  const int lo = lane & 15, hi = lane >> 4;
  const int wmi = wave >> 2, wni = wave & 3;
  const int swz = (lo & 7) << 4;

  const int nwg = gridDim.x;
  const int id = (blockIdx.x % 8) * (nwg >> 3) + blockIdx.x / 8;
  const int seg = id >> 8, idl = id & 255;
  const int row0 = (idl >> 2) * 256, col0 = (idl & 3) * 256;
  const bf16* Ap = (seg ? a1 : a0) + (size_t)row0 * 1024;
  const bf16* Bp = (seg ? b1 : b0) + (size_t)col0 * 1024;
  bf16* Cb = seg ? c1 : c0;

  const char* aSrc[2];
  const char* bSrc[2];
  int ldsOff[2];
#pragma unroll
  for (int rr = 0; rr < 2; ++rr) {
    const int x = rr * 8192 + tid * 16;
    const int lr = x >> 7;
    const int colx = (x & 127) ^ ((lr & 7) << 4);
    aSrc[rr] = (const char*)Ap + (size_t)(((lr >> 6) << 7) | (lr & 63)) * 2048 + colx;
    bSrc[rr] = (const char*)Bp + (size_t)(((lr >> 5) << 6) | (lr & 31)) * 2048 + colx;
    ldsOff[rr] = rr * 8192 + wave * 1024;
  }
  auto stA = [&](int h, int buf, int t) {
    const int tc = t > 15 ? 15 : t;
#pragma unroll
    for (int rr = 0; rr < 2; ++rr)
      gll16(aSrc[rr] + h * 131072 + tc * 128,
            ldsA + buf * 32768 + h * 16384 + ldsOff[rr]);
  };
  auto stB = [&](int h, int buf, int t) {
    const int tc = t > 15 ? 15 : t;
#pragma unroll
    for (int rr = 0; rr < 2; ++rr)
      gll16(bSrc[rr] + h * 65536 + tc * 128,
            ldsB + buf * 32768 + h * 16384 + ldsOff[rr]);
  };

  f32x4 acc[8][4] = {};
  bf16x8 af[4][2], bq0[2][2], bq1[2][2];

  auto rdA = [&](int mq, int buf) {
#pragma unroll
    for (int i = 0; i < 4; ++i) {
      const int lr = wmi * 64 + i * 16 + lo;
#pragma unroll
      for (int kh = 0; kh < 2; ++kh)
        af[i][kh] = *(const bf16x8*)(ldsA + buf * 32768 + mq * 16384 +
                                     lr * 128 + ((kh * 64 + hi * 16) ^ swz));
    }
  };
  auto rdB = [&](bf16x8 bq[2][2], int nq, int buf) {
#pragma unroll
    for (int n = 0; n < 2; ++n) {
      const int lr = wni * 32 + n * 16 + lo;
#pragma unroll
      for (int kh = 0; kh < 2; ++kh)
        bq[n][kh] = *(const bf16x8*)(ldsB + buf * 32768 + nq * 16384 +
                                     lr * 128 + ((kh * 64 + hi * 16) ^ swz));
    }
  };
  auto mma = [&](bf16x8 bq[2][2], int mq, int nq) {
    __builtin_amdgcn_s_setprio(1);
#pragma unroll
    for (int i = 0; i < 4; ++i)
#pragma unroll
      for (int n = 0; n < 2; ++n)
#pragma unroll
        for (int kh = 0; kh < 2; ++kh)
          acc[mq * 4 + i][nq * 2 + n] = __builtin_amdgcn_mfma_f32_16x16x32_bf16(
              af[i][kh], bq[n][kh], acc[mq * 4 + i][nq * 2 + n], 0, 0, 0);
    __builtin_amdgcn_s_setprio(0);
  };

  stA(0, 0, 0); stB(1, 0, 0); stA(1, 0, 0); stB(0, 0, 0);
  stA(0, 1, 1); stB(1, 1, 1); stA(1, 1, 1);
  VMW(6); BARR;

  for (int j = 0; j < 8; ++j) {
    const int t1 = 2 * j + 1, t2 = 2 * j + 2, t3 = 2 * j + 3;
    rdA(0, 0); rdB(bq0, 0, 0); stB(0, 1, t1);
    BARR; LGKM0; mma(bq0, 0, 0); BARR;
    rdB(bq1, 1, 0); stA(0, 0, t2);
    BARR; LGKM0; mma(bq1, 0, 1); BARR;
    rdA(1, 0); stB(1, 0, t2);
    BARR; LGKM0; mma(bq1, 1, 1); BARR;
    stA(1, 0, t2);
    BARR; LGKM0; mma(bq0, 1, 0); VMW(6); BARR;
    rdA(0, 1); rdB(bq0, 0, 1); stB(0, 0, t2);
    BARR; LGKM0; mma(bq0, 0, 0); BARR;
    rdB(bq1, 1, 1); stA(0, 1, t3);
    BARR; LGKM0; mma(bq1, 0, 1); BARR;
    rdA(1, 1); stB(1, 1, t3);
    BARR; LGKM0; mma(bq1, 1, 1); BARR;
    stA(1, 1, t3);
    BARR; LGKM0; mma(bq0, 1, 0); VMW(6); BARR;
  }

  if (!seg) {
#pragma unroll
    for (int m = 0; m < 8; ++m)
#pragma unroll
      for (int n = 0; n < 4; ++n) {
        const int c = col0 + wni * 64 + n * 16 + lo;
        const int rbase = row0 + wmi * 128 + m * 16 + hi * 4;
#pragma unroll
        for (int j = 0; j < 4; ++j)
          Cb[(size_t)(rbase + j) * 1024 + c] = (bf16)acc[m][n][j];
      }
  } else {
#pragma unroll
    for (int m = 0; m < 8; ++m)
#pragma unroll
      for (int n = 0; n < 4; ++n) {
        const int r = row0 + wmi * 128 + m * 16 + hi * 4;
        const int c = col0 + wni * 64 + n * 16 + lo;
        const int bb = r >> 10, tt = r & 1023;
        bf16x4 h = { (bf16)acc[m][n][0], (bf16)acc[m][n][1],
                     (bf16)acc[m][n][2], (bf16)acc[m][n][3] };
        *(bf16x4*)(Cb + ((size_t)bb << 20) + ((size_t)c << 10) + tt) = h;
      }
  }
  asm volatile("s_waitcnt vmcnt(0)" ::: "memory");
}

// ============================================================================
// 2-phase 128x128 BT-GEMM (BK=32), R14-proven core.
// VARIANT 0: P = BT(WkT,WqT) row-major bf16, M=N=1024, grid 64 (4x the
//   parallelism of the old 16-block 256-tile P -> ~half the serial bubble).
// VARIANT 2: qk S=BT(Y,Xk)/batch; causal writes 0, pad -inf; zero-fill iff
//   jt>=it+2. VARIANT 3: pv out f32, nt=min(32,4*it+5).
// ============================================================================
template <int VARIANT>
__global__ __launch_bounds__(512, 2) void gemm8(const bf16* __restrict__ a0,
                                                const bf16* __restrict__ b0,
                                                bf16* __restrict__ c0,
                                                float* __restrict__ Cf,
                                                const int* __restrict__ pad) {
  constexpr int TM = 128, TN = 128;
  constexpr int ABYTES = TM * 64;
  constexpr int BBYTES = TN * 64;
  constexpr int FI = TM / 64;                 // A frags per phase
  constexpr int FN = TN / 64;                 // B frags per wave
  extern __shared__ char smem[];
  char* ldsA = smem;
  char* ldsB = smem + 2 * ABYTES;

  const int tid = threadIdx.x;
  const int lane = tid & 63, wave = tid >> 6;
  const int lo = lane & 15, hi = lane >> 4;
  const int wmi = wave >> 2, wni = wave & 3;
  const int swz = ((lo >> 1) & 3) << 4;

  const int nwg = gridDim.x;
  const int id = (blockIdx.x % 8) * (nwg >> 3) + blockIdx.x / 8;

  int row0, col0, nt, batch = 0;
  if (VARIANT == 0) {
    row0 = (id >> 3) * 128; col0 = (id & 7) * 128; nt = 32;   // grid 64, 8x8 tiles
  } else {
    batch = id >> 6;
    const int it = (id >> 3) & 7, jt = id & 7;
    row0 = it * 128; col0 = jt * 128;
    nt = (VARIANT == 3) ? min(32, 4 * it + 5) : 32;
    if (VARIANT == 2 && jt >= it + 2) {        // fully above causal boundary
      bf16* Sb = c0 + ((size_t)batch << 20);
      bf16x8 z = {};
#pragma unroll
      for (int q = 0; q < (TM * TN) / (512 * 8); ++q) {
        const int off = (q * 512 + tid) * 8;
        *(bf16x8*)(Sb + (size_t)(row0 + (off >> 7)) * 1024 + col0 + (off & 127)) = z;
      }
      return;
    }
  }
  const bf16* Ap = a0 + ((size_t)batch << 20) + (size_t)row0 * 1024;
  const bf16* Bp = b0 + ((size_t)batch << 20) + (size_t)col0 * 1024;
  bf16* Cb = c0;
  const int ntm1 = nt - 1;

  auto stgA = [&](int tidx, int slot) {
    const int tc = tidx > ntm1 ? ntm1 : tidx;
    const int x  = tid * 16;
    const int xs = x ^ (((x >> 7) & 3) << 4);
    gll16((const char*)Ap + (size_t)(xs >> 6) * 2048 + (size_t)tc * 64 + (xs & 63),
          ldsA + slot * ABYTES + wave * 1024);
  };
  auto stgB = [&](int tidx, int slot) {
    const int tc = tidx > ntm1 ? ntm1 : tidx;
    const int x  = tid * 16;
    const int xs = x ^ (((x >> 7) & 3) << 4);
    gll16((const char*)Bp + (size_t)(xs >> 6) * 2048 + (size_t)tc * 64 + (xs & 63),
          ldsB + slot * BBYTES + wave * 1024);
  };

  f32x4 acc[2 * FI][FN] = {};
  bf16x8 af[FI], bfr[FN];

  auto rdA = [&](int mh, int slot) {
#pragma unroll
    for (int i = 0; i < FI; ++i) {
      const int row = wmi * (TM / 2) + mh * (TM / 4) + i * 16 + lo;
      af[i] = *(const bf16x8*)(ldsA + slot * ABYTES + ((row * 64 + hi * 16) ^ swz));
    }
  };
  auto rdB = [&](int slot) {
#pragma unroll
    for (int n = 0; n < FN; ++n) {
      const int row = wni * (TN / 4) + n * 16 + lo;
      bfr[n] = *(const bf16x8*)(ldsB + slot * BBYTES + ((row * 64 + hi * 16) ^ swz));
    }
  };
  auto mmaQ = [&](int mh) {
    __builtin_amdgcn_s_setprio(1);
#pragma unroll
    for (int i = 0; i < FI; ++i)
#pragma unroll
      for (int n = 0; n < FN; ++n)
        acc[mh * FI + i][n] = __builtin_amdgcn_mfma_f32_16x16x32_bf16(
            af[i], bfr[n], acc[mh * FI + i][n], 0, 0, 0);
    __builtin_amdgcn_s_setprio(0);
  };

  stgB(0, 0);
  stgA(0, 0);
  stgB(1, 1);
  VMW(1);
  BARR;

#pragma unroll 2
  for (int u = 0; u < nt; ++u) {
    const int cur = u & 1;
    rdA(0, cur);
    rdB(cur);
    stgA(u + 1, cur ^ 1);
    BARR; LGKM0;
    mmaQ(0);
    BARR;
    rdA(1, cur);
    stgB(u + 2, cur);
    BARR; LGKM0;
    mmaQ(1);
    VMW(1);
    BARR;
  }

  if (VARIANT == 0) {
#pragma unroll
    for (int m = 0; m < 2 * FI; ++m)
#pragma unroll
      for (int n = 0; n < FN; ++n) {
        const int c = col0 + wni * (TN / 4) + n * 16 + lo;
        const int rbase = row0 + wmi * (TM / 2) + m * 16 + hi * 4;
#pragma unroll
        for (int j = 0; j < 4; ++j)
          Cb[(size_t)(rbase + j) * 1024 + c] = (bf16)acc[m][n][j];
      }
  } else if (VARIANT == 2) {
    const float NINF = -__builtin_inff();
#pragma unroll
    for (int n = 0; n < FN; ++n) {
      const int s = col0 + wni * (TN / 4) + n * 16 + lo;
      const int pd = pad[(batch << 10) + s];
#pragma unroll
      for (int m = 0; m < 2 * FI; ++m) {
        const int tbase = row0 + wmi * (TM / 2) + m * 16 + hi * 4;
#pragma unroll
        for (int j = 0; j < 4; ++j) {
          float v = acc[m][n][j] * 0.03125f;
          if (s > tbase + j + 1) v = 0.f;
          else if (pd != 0) v = NINF;
          Cb[((size_t)batch << 20) + (size_t)(tbase + j) * 1024 + s] = (bf16)v;
        }
      }
    }
  } else {
#pragma unroll
    for (int m = 0; m < 2 * FI; ++m)
#pragma unroll
      for (int n = 0; n < FN; ++n) {
        const int h2 = col0 + wni * (TN / 4) + n * 16 + lo;
        const int tbase = row0 + wmi * (TM / 2) + m * 16 + hi * 4;
#pragma unroll
        for (int j = 0; j < 4; ++j)
          Cf[((size_t)batch << 20) + (size_t)(tbase + j) * 1024 + h2] = acc[m][n][j];
      }
  }
  asm volatile("s_waitcnt vmcnt(0)" ::: "memory");
}

// ---- all three inputs fp32 -> bf16 in one launch (8192 blocks each) ----
// Separate dispatch again: R15's merge with the LDS-heavy P path halved its
// occupancy and bandwidth (104 us @ 12% HBM). Dynamic LDS is per-launch.
__global__ __launch_bounds__(256) void cvt3_kernel(const float* __restrict__ s0,
                                                   const float* __restrict__ s1,
                                                   const float* __restrict__ s2,
                                                   bf16* __restrict__ d0,
                                                   bf16* __restrict__ d1,
                                                   bf16* __restrict__ d2) {
  const int seg = blockIdx.x >> 13, blk = blockIdx.x & 8191;
  const float* src = seg == 0 ? s0 : (seg == 1 ? s1 : s2);
  bf16* dst = seg == 0 ? d0 : (seg == 1 ? d1 : d2);
  const int i = (blk * 256 + threadIdx.x) * 8;
  const f32x4 a = *(const f32x4*)(src + i);
  const f32x4 b = *(const f32x4*)(src + i + 4);
  bf16x8 o = { (bf16)a[0], (bf16)a[1], (bf16)a[2], (bf16)a[3],
               (bf16)b[0], (bf16)b[1], (bf16)b[2], (bf16)b[3] };
  *(bf16x8*)(dst + i) = o;
}

// ---- weights: Wq,Wk -> TRANSPOSED bf16 (for the P-GEMM); Wv -> straight ----
__global__ __launch_bounds__(256) void cvtWT_kernel(const float* __restrict__ Wq,
                                                    const float* __restrict__ Wk,
                                                    const float* __restrict__ Wv,
                                                    bf16* __restrict__ WqT,
                                                    bf16* __restrict__ WkT,
                                                    bf16* __restrict__ Wvb) {
  const int t = threadIdx.x;
  if (blockIdx.x >= 512) {
    const int i = ((blockIdx.x - 512) * 256 + t) * 8;
    const f32x4 a = *(const f32x4*)(Wv + i);
    const f32x4 b = *(const f32x4*)(Wv + i + 4);
    bf16x8 o = { (bf16)a[0], (bf16)a[1], (bf16)a[2], (bf16)a[3],
                 (bf16)b[0], (bf16)b[1], (bf16)b[2], (bf16)b[3] };
    *(bf16x8*)(Wvb + i) = o;
    return;
  }
  const int m = blockIdx.x >> 8;
  const float* src = m ? Wk : Wq;
  bf16* dst = m ? WkT : WqT;
  const int tile = blockIdx.x & 255;
  const int tr = (tile >> 4) * 64, tc = (tile & 15) * 64;
  __shared__ bf16 s[64][72];
#pragma unroll
  for (int it = 0; it < 4; ++it) {
    const int row = it * 16 + (t >> 4), col = (t & 15) * 4;
    const f32x4 v = *(const f32x4*)(src + (size_t)(tr + row) * 1024 + tc + col);
#pragma unroll
    for (int j = 0; j < 4; ++j) s[col + j][row] = (bf16)v[j];
  }
  __syncthreads();
  const int c = t >> 2, rb = (t & 3) * 16;
  bf16* d = dst + (size_t)(tc + c) * 1024 + tr + rb;
  *(bf16x8*)(d)     = *(const bf16x8*)&s[c][rb];
  *(bf16x8*)(d + 8) = *(const bf16x8*)&s[c][rb + 8];
}

// ---- row softmax in place over valid prefix w = t+2 (causal tail stays 0) ----
__global__ __launch_bounds__(256) void softmax_kernel(bf16* __restrict__ S) {
  const int row  = blockIdx.x * 4 + (threadIdx.x >> 6);
  const int lane = threadIdx.x & 63;
  const int t = row & 1023;
  const int w = min(1024, t + 2);
  const bool act = lane * 16 < w;
  bf16* r = S + (size_t)row * 1024 + lane * 16;
  bf16x8 v0 = {}, v1 = {};
  float f[16];
#pragma unroll
  for (int j = 0; j < 16; ++j) f[j] = -1e30f;
  if (act) {
    v0 = *(const bf16x8*)r;
    v1 = *(const bf16x8*)(r + 8);
#pragma unroll
    for (int j = 0; j < 16; ++j)
      if (lane * 16 + j < w) f[j] = (float)(j < 8 ? v0[j] : v1[j - 8]);
  }
  float m = f[0];
#pragma unroll
  for (int j = 1; j < 16; ++j) m = fmaxf(m, f[j]);
#pragma unroll
  for (int o = 32; o; o >>= 1) m = fmaxf(m, __shfl_xor(m, o, 64));
  float sum = 0.f;
  float e[16];
#pragma unroll
  for (int j = 0; j < 16; ++j) { e[j] = __expf(f[j] - m); sum += e[j]; }
#pragma unroll
  for (int o = 32; o; o >>= 1) sum += __shfl_xor(sum, o, 64);
  const float inv = 1.0f / sum;
  if (act) {
#pragma unroll
    for (int j = 0; j < 8; ++j) {
      v0[j] = (bf16)(lane * 16 + j < w ? e[j] * inv : 0.f);
      v1[j] = (bf16)(lane * 16 + 8 + j < w ? e[8 + j] * inv : 0.f);
    }
    *(bf16x8*)r = v0;
    *(bf16x8*)(r + 8) = v1;
  }
}

extern "C" void kernel_launch(void* const* d_in, const int* in_sizes, int n_in,
                              void* d_out, int out_size, void* d_ws, size_t ws_size,
                              hipStream_t stream) {
  const float* key   = (const float*)d_in[0];
  const float* query = (const float*)d_in[1];
  const float* value = (const float*)d_in[2];
  const int*   pad   = (const int*)d_in[3];
  const float* Wk    = (const float*)d_in[4];
  const float* Wq    = (const float*)d_in[5];
  const float* Wv    = (const float*)d_in[6];
  float* out = (float*)d_out;

  // ws (bf16 elems): WqT,WkT,Wvb,P (1M each) | Y 16M | vT 16M | S 16M
  // Scratch: Xq = S slot (not live until qk writes S); Xk,Xv = d_out.
  bf16* WqT = (bf16*)d_ws;
  bf16* WkT = WqT + (1 << 20);
  bf16* Wvb = WkT + (1 << 20);
  bf16* P   = Wvb + (1 << 20);
  bf16* Y   = P   + (1 << 20);
  bf16* vT  = Y   + (16 << 20);
  bf16* S   = vT  + (16 << 20);
  bf16* Xq  = S;
  bf16* Xk  = (bf16*)d_out;
  bf16* Xv  = Xk + (16 << 20);

  hipFuncSetAttribute(reinterpret_cast<const void*>(&proj8),
                      hipFuncAttributeMaxDynamicSharedMemorySize, 131072);
  hipFuncSetAttribute(reinterpret_cast<const void*>(&gemm8<0>),
                      hipFuncAttributeMaxDynamicSharedMemorySize, 32768);
  hipFuncSetAttribute(reinterpret_cast<const void*>(&gemm8<2>),
                      hipFuncAttributeMaxDynamicSharedMemorySize, 32768);
  hipFuncSetAttribute(reinterpret_cast<const void*>(&gemm8<3>),
                      hipFuncAttributeMaxDynamicSharedMemorySize, 32768);

  cvtWT_kernel<<<1024, 256, 0, stream>>>(Wq, Wk, Wv, WqT, WkT, Wvb);
  // P[f,e] = sum_h Wk[h,f]*Wq[h,e] = BT(WkT, WqT); 64 blocks of 128x128
  gemm8<0><<<64, 512, 32768, stream>>>(WkT, WqT, P, nullptr, nullptr);
  cvt3_kernel<<<24576, 256, 0, stream>>>(query, key, value, Xq, Xk, Xv);

  // merged 8-phase projections: seg0 Y = BT(Xq, P); seg1 vT = BT(Xv, Wvb)^T
  proj8<<<512, 512, 131072, stream>>>(Xq, Xv, P, Wvb, Y, vT);

  // S = BT(Y, Xk) per batch (== q k^T), 128x128 tiles
  gemm8<2><<<1024, 512, 32768, stream>>>(Y, Xk, S, nullptr, pad);
  softmax_kernel<<<4096, 256, 0, stream>>>(S);
  gemm8<3><<<1024, 512, 32768, stream>>>(S, vT, nullptr, out, nullptr);
}